// Round 5
// baseline (460.535 us; speedup 1.0000x reference)
//
#include <hip/hip_runtime.h>
#include <hip/hip_cooperative_groups.h>
#include <stdint.h>

namespace cg = cooperative_groups;

#define H 128
#define TM 16
#define MAXDEG 16

typedef __attribute__((ext_vector_type(8))) short short8;
typedef __attribute__((ext_vector_type(4))) float f32x4;
typedef __attribute__((ext_vector_type(4))) int i32x4;

struct SmemT {
    short a_stage[TM * 264];   // 16 x (256+8 pad) bf16
    float o_stage[TM * 132];   // 16 x (128+4 pad) f32
    short emb_s[16 * 136];     // padded stride
};

__device__ __forceinline__ unsigned short f2bf(float f) {
    union { float f; unsigned u; } v; v.f = f;
    unsigned u = v.u;
    u += 0x7fffu + ((u >> 16) & 1u);   // round-to-nearest-even
    return (unsigned short)(u >> 16);
}

__device__ __forceinline__ float bf2f(unsigned short u) {
    union { unsigned u; float f; } v; v.u = ((unsigned)u) << 16; return v.f;
}

__device__ __forceinline__ short8 cvt8(f32x4 a, f32x4 b) {
    short8 r;
    r[0] = (short)f2bf(a.x); r[1] = (short)f2bf(a.y);
    r[2] = (short)f2bf(a.z); r[3] = (short)f2bf(a.w);
    r[4] = (short)f2bf(b.x); r[5] = (short)f2bf(b.y);
    r[6] = (short)f2bf(b.z); r[7] = (short)f2bf(b.w);
    return r;
}

// ---------------------------------------------------------------------------
// Phase-1 pieces (grid-stride)
// ---------------------------------------------------------------------------
__device__ __forceinline__ void dev_convert_x(
    const float* __restrict__ x, unsigned short* __restrict__ xb,
    int t8x, int gtid, int gsize)
{
    for (int i = gtid; i < t8x; i += gsize) {
        f32x4 a = ((const f32x4*)x)[2 * i];
        f32x4 b = ((const f32x4*)x)[2 * i + 1];
        ((short8*)xb)[i] = cvt8(a, b);
    }
}

__device__ __forceinline__ void dev_build(
    const int* __restrict__ ei, const int* __restrict__ et,
    int* __restrict__ cnt, int* __restrict__ bucket, int E, int gtid, int gsize)
{
    for (int e = gtid; e < E; e += gsize) {
        int src = ei[e];
        int dst = ei[E + e];
        int t   = et[e];
        int pos = atomicAdd(&cnt[dst], 1);
        if (pos < MAXDEG) bucket[(size_t)dst * MAXDEG + pos] = src | (t << 18);
    }
}

// ---------------------------------------------------------------------------
// Phase 2: per 16-node tile, gather+aggregate -> bf16 LDS A-tile -> K=256
// MFMA -> bias+relu -> LayerNorm -> NT store. Requires T <= 16 (emb in LDS).
// ---------------------------------------------------------------------------
__device__ void dev_phase2(SmemT& sm,
    const unsigned short* __restrict__ xb, const float* __restrict__ emb,
    const int* __restrict__ cnt, const int* __restrict__ bucket,
    const int* __restrict__ ei, const int* __restrict__ et,
    const float* __restrict__ Wself, const float* __restrict__ bself,
    const float* __restrict__ Wmsg, const float* __restrict__ bmsg,
    const float* __restrict__ gamma, const float* __restrict__ beta,
    float* __restrict__ out, int nTiles, int E, int T)
{
    const int tid  = threadIdx.x;
    const int wave = tid >> 6;
    const int lane = tid & 63;
    const int col  = lane & 15;
    const int quad = lane >> 4;
    const int node = tid >> 4;   // 0..15
    const int l    = tid & 15;   // feature chunk: elements l*8 .. l*8+7
    const int f0   = l * 8;

    // emb -> LDS as bf16, straight from fp32 (T<=16 -> 256 threads cover it)
    if (tid < T * 16) {
        const float* p = emb + (tid >> 4) * H + (tid & 15) * 8;
        f32x4 a = *(const f32x4*)p;
        f32x4 b = *(const f32x4*)(p + 4);
        *(short8*)&sm.emb_s[(tid >> 4) * 136 + (tid & 15) * 8] = cvt8(a, b);
    }

    // B fragments (weights, bf16) in registers; once per block
    short8 bfrag[2][8];
    float bias[2];
#pragma unroll
    for (int s = 0; s < 2; ++s) {
        const int h = (wave * 2 + s) * 16 + col;
        bias[s] = bself[h] + bmsg[h];
#pragma unroll
        for (int kst = 0; kst < 8; ++kst) {
            const float* W = (kst < 4) ? Wself : Wmsg;
            const int k0 = (kst & 3) * 32 + quad * 8;
            const float* p = W + (size_t)h * H + k0;
            f32x4 w0 = *(const f32x4*)(p);
            f32x4 w1 = *(const f32x4*)(p + 4);
            bfrag[s][kst] = cvt8(w0, w1);
        }
    }

    f32x4 g0  = *(const f32x4*)(gamma + f0);
    f32x4 g1  = *(const f32x4*)(gamma + f0 + 4);
    f32x4 be0 = *(const f32x4*)(beta + f0);
    f32x4 be1 = *(const f32x4*)(beta + f0 + 4);

    __syncthreads();   // emb_s visible

    for (int tile = blockIdx.x; tile < nTiles; tile += gridDim.x) {
        const size_t row = (size_t)tile * TM + node;

        // independent loads issued together: x-stage, bucket chunk 0, cnt
        short8 xv_st = *(const short8*)(xb + row * H + f0);
        const int* brow = bucket + row * MAXDEG;
        i32x4 p = *(const i32x4*)brow;      // does NOT depend on cnt
        int c = cnt[row];

        float acc[8] = {0.f, 0.f, 0.f, 0.f, 0.f, 0.f, 0.f, 0.f};
        if (c <= MAXDEG) {
            if (c > 0) {
                bool h1 = c > 1, h2 = c > 2, h3 = c > 3;
                short8 xv0, xv1, xv2, xv3, ev0, ev1, ev2, ev3;
                {
                    int s = p.x & 0x3FFFF, t = p.x >> 18;
                    xv0 = *(const short8*)(xb + (size_t)s * H + f0);
                    ev0 = *(const short8*)&sm.emb_s[t * 136 + f0];
                }
                if (h1) {
                    int s = p.y & 0x3FFFF, t = p.y >> 18;
                    xv1 = *(const short8*)(xb + (size_t)s * H + f0);
                    ev1 = *(const short8*)&sm.emb_s[t * 136 + f0];
                }
                if (h2) {
                    int s = p.z & 0x3FFFF, t = p.z >> 18;
                    xv2 = *(const short8*)(xb + (size_t)s * H + f0);
                    ev2 = *(const short8*)&sm.emb_s[t * 136 + f0];
                }
                if (h3) {
                    int s = p.w & 0x3FFFF, t = p.w >> 18;
                    xv3 = *(const short8*)(xb + (size_t)s * H + f0);
                    ev3 = *(const short8*)&sm.emb_s[t * 136 + f0];
                }
#pragma unroll
                for (int j = 0; j < 8; ++j) acc[j] += bf2f((unsigned short)xv0[j]) + bf2f((unsigned short)ev0[j]);
                if (h1) {
#pragma unroll
                    for (int j = 0; j < 8; ++j) acc[j] += bf2f((unsigned short)xv1[j]) + bf2f((unsigned short)ev1[j]);
                }
                if (h2) {
#pragma unroll
                    for (int j = 0; j < 8; ++j) acc[j] += bf2f((unsigned short)xv2[j]) + bf2f((unsigned short)ev2[j]);
                }
                if (h3) {
#pragma unroll
                    for (int j = 0; j < 8; ++j) acc[j] += bf2f((unsigned short)xv3[j]) + bf2f((unsigned short)ev3[j]);
                }
            }
            for (int i0 = 4; i0 < c; i0 += 4) {
                i32x4 q = *(const i32x4*)(brow + i0);
                int rem = c - i0;
                bool h1 = rem > 1, h2 = rem > 2, h3 = rem > 3;
                short8 xv0, xv1, xv2, xv3, ev0, ev1, ev2, ev3;
                {
                    int s = q.x & 0x3FFFF, t = q.x >> 18;
                    xv0 = *(const short8*)(xb + (size_t)s * H + f0);
                    ev0 = *(const short8*)&sm.emb_s[t * 136 + f0];
                }
                if (h1) {
                    int s = q.y & 0x3FFFF, t = q.y >> 18;
                    xv1 = *(const short8*)(xb + (size_t)s * H + f0);
                    ev1 = *(const short8*)&sm.emb_s[t * 136 + f0];
                }
                if (h2) {
                    int s = q.z & 0x3FFFF, t = q.z >> 18;
                    xv2 = *(const short8*)(xb + (size_t)s * H + f0);
                    ev2 = *(const short8*)&sm.emb_s[t * 136 + f0];
                }
                if (h3) {
                    int s = q.w & 0x3FFFF, t = q.w >> 18;
                    xv3 = *(const short8*)(xb + (size_t)s * H + f0);
                    ev3 = *(const short8*)&sm.emb_s[t * 136 + f0];
                }
#pragma unroll
                for (int j = 0; j < 8; ++j) acc[j] += bf2f((unsigned short)xv0[j]) + bf2f((unsigned short)ev0[j]);
                if (h1) {
#pragma unroll
                    for (int j = 0; j < 8; ++j) acc[j] += bf2f((unsigned short)xv1[j]) + bf2f((unsigned short)ev1[j]);
                }
                if (h2) {
#pragma unroll
                    for (int j = 0; j < 8; ++j) acc[j] += bf2f((unsigned short)xv2[j]) + bf2f((unsigned short)ev2[j]);
                }
                if (h3) {
#pragma unroll
                    for (int j = 0; j < 8; ++j) acc[j] += bf2f((unsigned short)xv3[j]) + bf2f((unsigned short)ev3[j]);
                }
            }
        } else {
            // Overflow escape hatch (deg > MAXDEG): rescan full edge list.
            for (int e = 0; e < E; ++e) {
                if (ei[E + e] == (int)row) {
                    int s = ei[e], t = et[e];
                    short8 xv = *(const short8*)(xb + (size_t)s * H + f0);
                    short8 ev = *(const short8*)&sm.emb_s[t * 136 + f0];
#pragma unroll
                    for (int j = 0; j < 8; ++j) acc[j] += bf2f((unsigned short)xv[j]) + bf2f((unsigned short)ev[j]);
                }
            }
        }

        // write both halves of the A-tile
        *(short8*)&sm.a_stage[node * 264 + f0] = xv_st;
        short8 ar;
#pragma unroll
        for (int j = 0; j < 8; ++j) ar[j] = (short)f2bf(acc[j]);
        *(short8*)&sm.a_stage[node * 264 + 128 + f0] = ar;
        __syncthreads();

        // MFMA over K=256
        short8 afr[8];
#pragma unroll
        for (int kst = 0; kst < 8; ++kst)
            afr[kst] = *(const short8*)(&sm.a_stage[col * 264 + kst * 32 + quad * 8]);

        f32x4 acc0 = {0.f, 0.f, 0.f, 0.f};
        f32x4 acc1 = {0.f, 0.f, 0.f, 0.f};
#pragma unroll
        for (int kst = 0; kst < 8; ++kst) {
            acc0 = __builtin_amdgcn_mfma_f32_16x16x32_bf16(afr[kst], bfrag[0][kst], acc0, 0, 0, 0);
            acc1 = __builtin_amdgcn_mfma_f32_16x16x32_bf16(afr[kst], bfrag[1][kst], acc1, 0, 0, 0);
        }

        // bias + relu -> o_stage
#pragma unroll
        for (int s = 0; s < 2; ++s) {
            const int h = (wave * 2 + s) * 16 + col;
            f32x4 a = s ? acc1 : acc0;
#pragma unroll
            for (int r = 0; r < 4; ++r) {
                const int m = quad * 4 + r;
                float v = a[r] + bias[s];
                sm.o_stage[m * 132 + h] = v > 0.f ? v : 0.f;
            }
        }
        __syncthreads();

        // LayerNorm per node (16 lanes/node, 8 feats/lane)
        float v[8];
        float s1 = 0.f, s2 = 0.f;
#pragma unroll
        for (int j = 0; j < 8; ++j) {
            v[j] = sm.o_stage[node * 132 + f0 + j];
            s1 += v[j];
            s2 += v[j] * v[j];
        }
#pragma unroll
        for (int m = 1; m < 16; m <<= 1) {
            s1 += __shfl_xor(s1, m, 64);
            s2 += __shfl_xor(s2, m, 64);
        }
        const float mu = s1 * (1.f / 128.f);
        const float var = s2 * (1.f / 128.f) - mu * mu;
        const float rstd = rsqrtf(var + 1e-5f);

        f32x4 o0, o1;
        o0.x = (v[0] - mu) * rstd * g0.x + be0.x;
        o0.y = (v[1] - mu) * rstd * g0.y + be0.y;
        o0.z = (v[2] - mu) * rstd * g0.z + be0.z;
        o0.w = (v[3] - mu) * rstd * g0.w + be0.w;
        o1.x = (v[4] - mu) * rstd * g1.x + be1.x;
        o1.y = (v[5] - mu) * rstd * g1.y + be1.y;
        o1.z = (v[6] - mu) * rstd * g1.z + be1.z;
        o1.w = (v[7] - mu) * rstd * g1.w + be1.w;

        float* dst = out + row * H + f0;
        __builtin_nontemporal_store(o0, (f32x4*)dst);
        __builtin_nontemporal_store(o1, (f32x4*)(dst + 4));
    }
}

// ---------------------------------------------------------------------------
// Mono cooperative kernel: convert + build, grid.sync, fused gemm.
// ---------------------------------------------------------------------------
__global__ __launch_bounds__(256) void mono_kernel(
    const float* __restrict__ x, const float* __restrict__ emb,
    const int* __restrict__ ei, const int* __restrict__ et,
    unsigned short* __restrict__ xb, int* __restrict__ cnt,
    int* __restrict__ bucket,
    const float* __restrict__ Wself, const float* __restrict__ bself,
    const float* __restrict__ Wmsg, const float* __restrict__ bmsg,
    const float* __restrict__ gamma, const float* __restrict__ beta,
    float* __restrict__ out, int N, int E, int T, int nTiles)
{
    __shared__ SmemT sm;
    const int gsize = gridDim.x * 256;
    const int gtid  = blockIdx.x * 256 + threadIdx.x;
    dev_convert_x(x, xb, N * (H / 8), gtid, gsize);
    dev_build(ei, et, cnt, bucket, E, gtid, gsize);
    cg::this_grid().sync();
    dev_phase2(sm, xb, emb, cnt, bucket, ei, et,
               Wself, bself, Wmsg, bmsg, gamma, beta, out, nTiles, E, T);
}

// Non-cooperative fallback pair.
__global__ __launch_bounds__(256) void prep_kernel(
    const float* __restrict__ x, const int* __restrict__ ei,
    const int* __restrict__ et, unsigned short* __restrict__ xb,
    int* __restrict__ cnt, int* __restrict__ bucket, int N, int E)
{
    const int gsize = gridDim.x * 256;
    const int gtid  = blockIdx.x * 256 + threadIdx.x;
    dev_convert_x(x, xb, N * (H / 8), gtid, gsize);
    dev_build(ei, et, cnt, bucket, E, gtid, gsize);
}

__global__ __launch_bounds__(256) void fused_kernel(
    const unsigned short* __restrict__ xb, const float* __restrict__ emb,
    const int* __restrict__ cnt, const int* __restrict__ bucket,
    const int* __restrict__ ei, const int* __restrict__ et,
    const float* __restrict__ Wself, const float* __restrict__ bself,
    const float* __restrict__ Wmsg, const float* __restrict__ bmsg,
    const float* __restrict__ gamma, const float* __restrict__ beta,
    float* __restrict__ out, int nTiles, int E, int T)
{
    __shared__ SmemT sm;
    dev_phase2(sm, xb, emb, cnt, bucket, ei, et,
               Wself, bself, Wmsg, bmsg, gamma, beta, out, nTiles, E, T);
}

// ---------------------------------------------------------------------------
// Tier-C fallback: atomic scatter + fp32 gemm (agg staged in d_out).
// ---------------------------------------------------------------------------
__global__ __launch_bounds__(256) void scatter_kernel(
    const float* __restrict__ x, const int* __restrict__ ei,
    const int* __restrict__ et, const float* __restrict__ emb,
    float* __restrict__ agg, int E)
{
    int g = blockIdx.x * 256 + threadIdx.x;
    int e = g >> 5;
    int l = g & 31;
    if (e >= E) return;
    int src = ei[e];
    int dst = ei[E + e];
    int t   = et[e];
    f32x4 xv = *(const f32x4*)(x   + (size_t)src * H + l * 4);
    f32x4 ev = *(const f32x4*)(emb + (size_t)t   * H + l * 4);
    float* b = agg + (size_t)dst * H + l * 4;
    atomicAdd(b + 0, xv.x + ev.x);
    atomicAdd(b + 1, xv.y + ev.y);
    atomicAdd(b + 2, xv.z + ev.z);
    atomicAdd(b + 3, xv.w + ev.w);
}

__global__ __launch_bounds__(256) void gemm_ln_f32_kernel(
    const float* __restrict__ x,
    const float* __restrict__ Wself, const float* __restrict__ bself,
    const float* __restrict__ Wmsg, const float* __restrict__ bmsg,
    const float* __restrict__ gamma, const float* __restrict__ beta,
    float* __restrict__ out, int nTiles)
{
    __shared__ __align__(16) short a_stage[TM * 264];
    __shared__ __align__(16) float o_stage[TM * 132];

    const int tid  = threadIdx.x;
    const int wave = tid >> 6;
    const int lane = tid & 63;
    const int col  = lane & 15;
    const int quad = lane >> 4;

    short8 bfrag[2][8];
    float bias[2];
#pragma unroll
    for (int s = 0; s < 2; ++s) {
        const int h = (wave * 2 + s) * 16 + col;
        bias[s] = bself[h] + bmsg[h];
#pragma unroll
        for (int kst = 0; kst < 8; ++kst) {
            const float* W = (kst < 4) ? Wself : Wmsg;
            const int k0 = (kst & 3) * 32 + quad * 8;
            const float* p = W + (size_t)h * H + k0;
            f32x4 w0 = *(const f32x4*)(p);
            f32x4 w1 = *(const f32x4*)(p + 4);
            bfrag[s][kst] = cvt8(w0, w1);
        }
    }

    const int lnode = tid >> 4;
    const int f0 = (tid & 15) * 8;
    f32x4 g0  = *(const f32x4*)(gamma + f0);
    f32x4 g1  = *(const f32x4*)(gamma + f0 + 4);
    f32x4 be0 = *(const f32x4*)(beta + f0);
    f32x4 be1 = *(const f32x4*)(beta + f0 + 4);

    for (int tile = blockIdx.x; tile < nTiles; tile += gridDim.x) {
        const size_t rowBase = (size_t)tile * TM;
        {
            const int node = tid >> 4;
            const int seg  = tid & 15;
            const int k0   = seg * 16;
            const float* src = (seg < 8)
                ? (x   + (rowBase + node) * H + k0)
                : (out + (rowBase + node) * H + (k0 - 128));
            f32x4 v0 = ((const f32x4*)src)[0];
            f32x4 v1 = ((const f32x4*)src)[1];
            f32x4 v2 = ((const f32x4*)src)[2];
            f32x4 v3 = ((const f32x4*)src)[3];
            *(short8*)(&a_stage[node * 264 + k0])     = cvt8(v0, v1);
            *(short8*)(&a_stage[node * 264 + k0 + 8]) = cvt8(v2, v3);
        }
        __syncthreads();

        short8 afr[8];
#pragma unroll
        for (int kst = 0; kst < 8; ++kst)
            afr[kst] = *(const short8*)(&a_stage[col * 264 + kst * 32 + quad * 8]);

        f32x4 acc0 = {0.f, 0.f, 0.f, 0.f};
        f32x4 acc1 = {0.f, 0.f, 0.f, 0.f};
#pragma unroll
        for (int kst = 0; kst < 8; ++kst) {
            acc0 = __builtin_amdgcn_mfma_f32_16x16x32_bf16(afr[kst], bfrag[0][kst], acc0, 0, 0, 0);
            acc1 = __builtin_amdgcn_mfma_f32_16x16x32_bf16(afr[kst], bfrag[1][kst], acc1, 0, 0, 0);
        }

#pragma unroll
        for (int s = 0; s < 2; ++s) {
            const int h = (wave * 2 + s) * 16 + col;
            f32x4 a = s ? acc1 : acc0;
#pragma unroll
            for (int r = 0; r < 4; ++r) {
                const int m = quad * 4 + r;
                float v = a[r] + bias[s];
                o_stage[m * 132 + h] = v > 0.f ? v : 0.f;
            }
        }
        __syncthreads();

        float v[8];
        float s1 = 0.f, s2 = 0.f;
#pragma unroll
        for (int j = 0; j < 8; ++j) {
            v[j] = o_stage[lnode * 132 + f0 + j];
            s1 += v[j];
            s2 += v[j] * v[j];
        }
#pragma unroll
        for (int m = 1; m < 16; m <<= 1) {
            s1 += __shfl_xor(s1, m, 64);
            s2 += __shfl_xor(s2, m, 64);
        }
        const float mu = s1 * (1.f / 128.f);
        const float var = s2 * (1.f / 128.f) - mu * mu;
        const float rstd = rsqrtf(var + 1e-5f);

        f32x4 o0, o1;
        o0.x = (v[0] - mu) * rstd * g0.x + be0.x;
        o0.y = (v[1] - mu) * rstd * g0.y + be0.y;
        o0.z = (v[2] - mu) * rstd * g0.z + be0.z;
        o0.w = (v[3] - mu) * rstd * g0.w + be0.w;
        o1.x = (v[4] - mu) * rstd * g1.x + be1.x;
        o1.y = (v[5] - mu) * rstd * g1.y + be1.y;
        o1.z = (v[6] - mu) * rstd * g1.z + be1.z;
        o1.w = (v[7] - mu) * rstd * g1.w + be1.w;

        float* dst = out + (rowBase + lnode) * H + f0;
        *(f32x4*)(dst)     = o0;
        *(f32x4*)(dst + 4) = o1;
    }
}

extern "C" void kernel_launch(void* const* d_in, const int* in_sizes, int n_in,
                              void* d_out, int out_size, void* d_ws, size_t ws_size,
                              hipStream_t stream) {
    const float* x     = (const float*)d_in[0];
    const int*   ei    = (const int*)d_in[1];
    const int*   et    = (const int*)d_in[2];
    const float* emb   = (const float*)d_in[3];
    const float* Wself = (const float*)d_in[4];
    const float* bself = (const float*)d_in[5];
    const float* Wmsg  = (const float*)d_in[6];
    const float* bmsg  = (const float*)d_in[7];
    const float* gamma = (const float*)d_in[8];
    const float* beta  = (const float*)d_in[9];
    float* out = (float*)d_out;

    const int E = in_sizes[2];
    const int N = in_sizes[0] / H;
    const int T = in_sizes[3] / H;
    const int nTiles = N / TM;

    auto rnd = [](size_t b) { return (b + 255) & ~(size_t)255; };
    const size_t sz_xb  = rnd((size_t)N * H * 2);
    const size_t sz_cnt = rnd((size_t)N * 4);
    const size_t sz_bkt = rnd((size_t)N * MAXDEG * 4);
    const size_t need = sz_xb + sz_cnt + sz_bkt;

    const bool tierA = (ws_size >= need) && (N <= (1 << 18)) && (T <= 16)
                       && (N % TM == 0);

    if (tierA) {
        uint8_t* p = (uint8_t*)d_ws;
        unsigned short* xb = (unsigned short*)p;  p += sz_xb;
        int* cnt    = (int*)p;                    p += sz_cnt;
        int* bucket = (int*)p;

        hipMemsetAsync(cnt, 0, (size_t)N * sizeof(int), stream);

        // ---- cooperative mono-kernel path ----
        bool coop_done = false;
        int maxB = 0;
        hipError_t oe = hipOccupancyMaxActiveBlocksPerMultiprocessor(
            &maxB, reinterpret_cast<const void*>(mono_kernel), 256, 0);
        if (oe == hipSuccess && maxB > 0) {
            hipDeviceProp_t props;
            int dev = 0;
            if (hipGetDevice(&dev) == hipSuccess &&
                hipGetDeviceProperties(&props, dev) == hipSuccess) {
                long long grid = (long long)maxB * props.multiProcessorCount;
                if (grid > 65535) grid = 65535;
                if (grid >= 64) {
                    int Ni = N, Ei = E, Ti = T, nT = nTiles;
                    void* args[] = {
                        (void*)&x, (void*)&emb, (void*)&ei, (void*)&et,
                        (void*)&xb, (void*)&cnt, (void*)&bucket,
                        (void*)&Wself, (void*)&bself, (void*)&Wmsg, (void*)&bmsg,
                        (void*)&gamma, (void*)&beta, (void*)&out,
                        (void*)&Ni, (void*)&Ei, (void*)&Ti, (void*)&nT };
                    hipError_t le = hipLaunchCooperativeKernel(
                        reinterpret_cast<const void*>(mono_kernel),
                        dim3((unsigned)grid), dim3(256), args, 0, stream);
                    coop_done = (le == hipSuccess);
                }
            }
        }

        if (!coop_done) {
            // non-cooperative fallback: two dispatches
            const int t8x = N * (H / 8);
            int prepWork = t8x > E ? t8x : E;
            prep_kernel<<<(prepWork + 255) / 256, 256, 0, stream>>>(
                x, ei, et, xb, cnt, bucket, N, E);
            int grid = 3125;
            if (grid > nTiles) grid = nTiles;
            fused_kernel<<<grid, 256, 0, stream>>>(
                xb, emb, cnt, bucket, ei, et,
                Wself, bself, Wmsg, bmsg, gamma, beta, out, nTiles, E, T);
        }
    } else {
        // Tier C: atomic scatter into d_out, then fp32 gemm.
        hipMemsetAsync(out, 0, (size_t)N * H * sizeof(float), stream);
        const long long sthreads = (long long)E * 32;
        scatter_kernel<<<(int)((sthreads + 255) / 256), 256, 0, stream>>>(
            x, ei, et, emb, out, E);
        int grid = 2500;
        if (grid > nTiles) grid = nTiles;
        gemm_ln_f32_kernel<<<grid, 256, 0, stream>>>(
            x, Wself, bself, Wmsg, bmsg, gamma, beta, out, nTiles);
    }
}